// Round 8
// baseline (246.757 us; speedup 1.0000x reference)
//
#include <hip/hip_runtime.h>
#include <math.h>

// CRDLoss on MI355X.
// Phase 0: cvt W->fp16 (proven); same blocks zero the 64KB ssq arrays.
// Phase 1a: embed_mm -- barrier-free streaming GEMM. Each block: 32 output
//           cols, B-slab 32x2048 fp16 = 128KB LDS loaded ONCE (1 barrier);
//           4 waves independently stream 16-row A tiles global->reg with a
//           depth-8 named ring, MFMA vs swizzled LDS B, write h+bias fp16
//           and atomicAdd per-row sumsq.  grid (128,2) = 1 block/CU,
//           __launch_bounds__(256,1) so the ring fits registers.
// Phase 1b: embed_norm -- in-place row normalize of fs/ft using ssq.
// Phase 2:  loss -- 128x128 f16-MFMA tiles, log2-domain epilogue -> partials.
// Phase 3:  finalize -- reduce partials + y histogram -> loss (R10-proven).

typedef _Float16 half_t;
typedef half_t halfx4 __attribute__((ext_vector_type(4)));
typedef half_t halfx8 __attribute__((ext_vector_type(8)));
typedef float f32x4 __attribute__((ext_vector_type(4)));

#define B_TOT   8192
#define K_EMB   2048
#define F_DIM   128
#define EPS_C   0.97f
#define CU_L2   20.60992915555662f    // (1/T) * log2(e)
#define LN2_D   0.6931471805599453
#define LNEPS_D (-0.030459207484708574)  // ln(0.97), double

__device__ __forceinline__ float fexp2(float x) {
#if __has_builtin(__builtin_amdgcn_exp2f)
    return __builtin_amdgcn_exp2f(x);
#else
    return __expf(x * 0.6931471805599453f);
#endif
}
__device__ __forceinline__ float flog2(float x) {
#if __has_builtin(__builtin_amdgcn_logf)
    return __builtin_amdgcn_logf(x);
#else
    return __logf(x) * 1.4426950408889634f;
#endif
}

__device__ __forceinline__ void gload_lds16(const void* g, void* l)
{
    __builtin_amdgcn_global_load_lds(
        (const __attribute__((address_space(1))) void*)g,
        (__attribute__((address_space(3))) void*)l,
        16, 0, 0);
}

// ---------------------------------------------------------------------------
// W fp32 -> fp16.  grid = (256, 2); block = 256; one float4 per thread.
// Blocks (bx<64, by==0) also zero the ssq accumulators (16384 floats).
// ---------------------------------------------------------------------------
__global__ __launch_bounds__(256) void cvt_w_kernel(
    const float* __restrict__ Ws, const float* __restrict__ Wt,
    half_t* __restrict__ Ws16, half_t* __restrict__ Wt16,
    float* __restrict__ ssqs, float* __restrict__ ssqt)
{
    if (blockIdx.y == 0 && blockIdx.x < 64) {
        int idx = blockIdx.x * 256 + threadIdx.x;   // 0..16383
        if (idx < B_TOT) ssqs[idx] = 0.f;
        else             ssqt[idx - B_TOT] = 0.f;
    }
    const float* src = blockIdx.y ? Wt : Ws;
    half_t* dst = blockIdx.y ? Wt16 : Ws16;
    int pos4 = blockIdx.x * 256 + threadIdx.x;      // 0..65535
    float4 v = *(const float4*)(src + (size_t)pos4 * 4);
    halfx4 h4 = {(half_t)v.x, (half_t)v.y, (half_t)v.z, (half_t)v.w};
    *(halfx4*)(dst + (size_t)pos4 * 4) = h4;
}

// ---------------------------------------------------------------------------
// embed_mm: grid (128, 2); block 256 (4 waves).
// bx: rg = bx>>2 (row group of 256), ns = bx&3 (col group of 32: n0=ns*32).
// B-slab LDS (uint4 quads): slabq[col*256 + kblk*16 + slot] holds W quad
// kblk*16 + (slot ^ (col&15))  (proven 0-conflict XOR swizzle; gll linear
// dest + pre-swizzled source).  Loaded once, 1 barrier, then barrier-free.
// Main loop per wave: 4 tiles x 16 rows; per 32-K chunk: 2 A float4 loads
// (depth-8 ring), 2 swizzled ds_read_b128 (B), cvt, 2 MFMA.
// Epilogue: +bias, fp16 store (un-normalized), atomicAdd row sumsq.
// ---------------------------------------------------------------------------
__global__ __launch_bounds__(256, 1) void embed_mm_kernel(
    const float* __restrict__ Xs, const float* __restrict__ Xt,
    const half_t* __restrict__ Ws16, const half_t* __restrict__ Wt16,
    const float* __restrict__ bs, const float* __restrict__ bt,
    half_t* __restrict__ outs, half_t* __restrict__ outt,
    float* __restrict__ ssqs, float* __restrict__ ssqt)
{
    const float* X; const half_t* W16; const float* bias;
    half_t* out; float* ssq;
    if (blockIdx.y == 0) { X = Xs; W16 = Ws16; bias = bs; out = outs; ssq = ssqs; }
    else                 { X = Xt; W16 = Wt16; bias = bt; out = outt; ssq = ssqt; }

    __shared__ uint4 slabq[32 * 256];   // 128 KB

    const int tid  = threadIdx.x;
    const int lane = tid & 63;
    const int wv   = tid >> 6;          // 0..3
    const int l16  = lane & 15, lhi = lane >> 4;
    const int rg   = blockIdx.x >> 2;   // 0..31
    const int ns   = blockIdx.x & 3;    // 0..3
    const int n0   = ns * 32;
    const int rbase = rg * 256;

    const float bv0 = bias[n0 + l16];
    const float bv1 = bias[n0 + 16 + l16];

    // ---- B-slab load: 128 gll instrs total, 32 per wave -------------------
    for (int i = 0; i < 32; ++i) {
        const int g   = wv * 32 + i;
        const int col = g >> 2;
        const int kb0 = (g & 3) * 4;
        const half_t* src = W16 + (size_t)(n0 + col) * K_EMB
            + (size_t)(((kb0 + (lane >> 4)) * 16 + ((lane & 15) ^ (col & 15))) * 8);
        gload_lds16(src, &slabq[col * 256 + kb0 * 16]);
    }
    asm volatile("s_waitcnt vmcnt(0)" ::: "memory");
    __builtin_amdgcn_s_barrier();

    // swizzled slot per (chunk&3); B quad for chunk C = C*4+lhi
    const int slot0 = (0 * 4 + lhi) ^ l16;
    const int slot1 = (1 * 4 + lhi) ^ l16;
    const int slot2 = (2 * 4 + lhi) ^ l16;
    const int slot3 = (3 * 4 + lhi) ^ l16;
    const int qrow0 = l16 * 256;          // B col = l16
    const int qrow1 = (16 + l16) * 256;   // B col = 16 + l16

#define CH_LOAD(J, C) do {                                                     \
        r0[J] = *(const float4*)(ap + (size_t)(C) * 32);                       \
        r1[J] = *(const float4*)(ap + (size_t)(C) * 32 + 4);                   \
    } while (0)

#define CH_BODY(J, C, SLOT) do {                                               \
        halfx8 af = {(half_t)r0[J].x, (half_t)r0[J].y, (half_t)r0[J].z,        \
                     (half_t)r0[J].w, (half_t)r1[J].x, (half_t)r1[J].y,        \
                     (half_t)r1[J].z, (half_t)r1[J].w};                        \
        const int qb = ((C) >> 2) * 16;                                        \
        halfx8 b0 = *(const halfx8*)&slabq[qrow0 + qb + (SLOT)];               \
        halfx8 b1 = *(const halfx8*)&slabq[qrow1 + qb + (SLOT)];               \
        acc0 = __builtin_amdgcn_mfma_f32_16x16x32_f16(af, b0, acc0, 0, 0, 0);  \
        acc1 = __builtin_amdgcn_mfma_f32_16x16x32_f16(af, b1, acc1, 0, 0, 0);  \
    } while (0)

    for (int ti = 0; ti < 4; ++ti) {
        const int rtile = rbase + wv * 64 + ti * 16;
        const float* ap = X + (size_t)(rtile + l16) * K_EMB + lhi * 8;

        f32x4 acc0 = f32x4{0.f, 0.f, 0.f, 0.f};
        f32x4 acc1 = f32x4{0.f, 0.f, 0.f, 0.f};

        float4 r0[8], r1[8];    // literal-indexed only -> registers
        CH_LOAD(0, 0); CH_LOAD(1, 1); CH_LOAD(2, 2); CH_LOAD(3, 3);
        CH_LOAD(4, 4); CH_LOAD(5, 5); CH_LOAD(6, 6); CH_LOAD(7, 7);

#pragma unroll 1
        for (int c = 0; c < 56; c += 8) {
            CH_BODY(0, c + 0, slot0); CH_LOAD(0, c + 8);
            CH_BODY(1, c + 1, slot1); CH_LOAD(1, c + 9);
            CH_BODY(2, c + 2, slot2); CH_LOAD(2, c + 10);
            CH_BODY(3, c + 3, slot3); CH_LOAD(3, c + 11);
            CH_BODY(4, c + 4, slot0); CH_LOAD(4, c + 12);
            CH_BODY(5, c + 5, slot1); CH_LOAD(5, c + 13);
            CH_BODY(6, c + 6, slot2); CH_LOAD(6, c + 14);
            CH_BODY(7, c + 7, slot3); CH_LOAD(7, c + 15);
        }
        CH_BODY(0, 56, slot0); CH_BODY(1, 57, slot1);
        CH_BODY(2, 58, slot2); CH_BODY(3, 59, slot3);
        CH_BODY(4, 60, slot0); CH_BODY(5, 61, slot1);
        CH_BODY(6, 62, slot2); CH_BODY(7, 63, slot3);

        // tile epilogue: +bias, fp16 store (un-normalized), row sumsq
#pragma unroll
        for (int reg = 0; reg < 4; ++reg) {
            float v0 = acc0[reg] + bv0;
            float v1 = acc1[reg] + bv1;
            const int rowg = rtile + lhi * 4 + reg;
            out[(size_t)rowg * F_DIM + n0 + l16]      = (half_t)v0;
            out[(size_t)rowg * F_DIM + n0 + 16 + l16] = (half_t)v1;
            float p = v0 * v0 + v1 * v1;
            p += __shfl_xor(p, 1);
            p += __shfl_xor(p, 2);
            p += __shfl_xor(p, 4);
            p += __shfl_xor(p, 8);
            if (l16 == 0) atomicAdd(&ssq[rowg], p);
        }
    }
#undef CH_LOAD
#undef CH_BODY
}

// ---------------------------------------------------------------------------
// embed_norm: in-place row-normalize fp16 h using ssq[row].
// grid (256, 2); block 256.  Block: 32 rows; thread: row tid>>3, 16 cols.
// ---------------------------------------------------------------------------
__global__ __launch_bounds__(256) void embed_norm_kernel(
    half_t* __restrict__ fs, half_t* __restrict__ ft,
    const float* __restrict__ ssqs, const float* __restrict__ ssqt)
{
    half_t* h = blockIdx.y ? ft : fs;
    const float* ssq = blockIdx.y ? ssqt : ssqs;

    __shared__ float inv[32];
    const int r0 = blockIdx.x * 32;
    if (threadIdx.x < 32)
        inv[threadIdx.x] = rsqrtf(ssq[r0 + threadIdx.x]);
    __syncthreads();

    const int row = threadIdx.x >> 3;
    const int c0  = (threadIdx.x & 7) * 16;
    half_t* p = h + (size_t)(r0 + row) * F_DIM + c0;
    const float iv = inv[row];
    halfx8 u0 = *(halfx8*)p;
    halfx8 u1 = *(halfx8*)(p + 8);
    halfx8 o0, o1;
#pragma unroll
    for (int j = 0; j < 8; ++j) {
        o0[j] = (half_t)((float)u0[j] * iv);
        o1[j] = (half_t)((float)u1[j] * iv);
    }
    *(halfx8*)p       = o0;
    *(halfx8*)(p + 8) = o1;
}

// ---------------------------------------------------------------------------
// Loss: 128x128 tile of fs·ft^T, K=128 in two 64-wide LDS chunks (33 KB LDS).
// grid = (64, 64); block = 256.  (unchanged R10/R13-proven)
// ---------------------------------------------------------------------------
__global__ __launch_bounds__(256) void loss_kernel(
    const half_t* __restrict__ FS, const half_t* __restrict__ FT,
    const int* __restrict__ y, double* __restrict__ partials)
{
    __shared__ uint4 As4[128 * 8];   // 16 KB
    __shared__ uint4 Bs4[128 * 8];   // 16 KB
    __shared__ int   yrl[128], ycl[128];
    __shared__ float wsum[4];

    const int tid = threadIdx.x;
    const int i0  = blockIdx.x * 128;
    const int j0  = blockIdx.y * 128;

    if (tid < 128) yrl[tid] = y[i0 + tid];
    else           ycl[tid - 128] = y[j0 + tid - 128];

    const int lane = tid & 63;
    const int w    = tid >> 6;
    const int wm   = w >> 1, wn = w & 1;
    const int l16  = lane & 15, lhi = lane >> 4;

#pragma unroll
    for (int i = 0; i < 4; ++i) {
        int f = tid + i * 256;
        int row = f >> 3, c = f & 7;
        As4[row * 8 + (c ^ (row & 7))] = *(const uint4*)(FS + (size_t)(i0 + row) * F_DIM + c * 8);
    }
#pragma unroll
    for (int i = 0; i < 4; ++i) {
        int f = tid + i * 256;
        int row = f >> 3, c = f & 7;
        Bs4[row * 8 + (c ^ (row & 7))] = *(const uint4*)(FT + (size_t)(j0 + row) * F_DIM + c * 8);
    }
    __syncthreads();

    f32x4 acc[4][4];
    for (int im = 0; im < 4; ++im)
        for (int in = 0; in < 4; ++in)
            acc[im][in] = f32x4{0.f, 0.f, 0.f, 0.f};

    for (int kc = 0; kc < 2; ++kc) {
#pragma unroll
        for (int kk = 0; kk < 2; ++kk) {
            halfx8 a[4], b[4];
#pragma unroll
            for (int im = 0; im < 4; ++im) {
                int r = wm * 64 + im * 16 + l16;
                a[im] = *(const halfx8*)&As4[r * 8 + ((kk * 4 + lhi) ^ (r & 7))];
            }
#pragma unroll
            for (int in = 0; in < 4; ++in) {
                int r = wn * 64 + in * 16 + l16;
                b[in] = *(const halfx8*)&Bs4[r * 8 + ((kk * 4 + lhi) ^ (r & 7))];
            }
#pragma unroll
            for (int im = 0; im < 4; ++im)
#pragma unroll
                for (int in = 0; in < 4; ++in)
                    acc[im][in] = __builtin_amdgcn_mfma_f32_16x16x32_f16(
                        a[im], b[in], acc[im][in], 0, 0, 0);
        }
        if (kc == 0) {
            __syncthreads();
#pragma unroll
            for (int i = 0; i < 4; ++i) {
                int f = tid + i * 256;
                int row = f >> 3, c = f & 7;
                As4[row * 8 + (c ^ (row & 7))] =
                    *(const uint4*)(FS + (size_t)(i0 + row) * F_DIM + 64 + c * 8);
            }
#pragma unroll
            for (int i = 0; i < 4; ++i) {
                int f = tid + i * 256;
                int row = f >> 3, c = f & 7;
                Bs4[row * 8 + (c ^ (row & 7))] =
                    *(const uint4*)(FT + (size_t)(j0 + row) * F_DIM + 64 + c * 8);
            }
            __syncthreads();
        }
    }

    int yclv[4];
#pragma unroll
    for (int in = 0; in < 4; ++in) yclv[in] = ycl[wn * 64 + in * 16 + l16];

    float sumL = 0.f, sumU = 0.f;
    if (i0 != j0) {
#pragma unroll
        for (int im = 0; im < 4; ++im)
#pragma unroll
            for (int reg = 0; reg < 4; ++reg) {
                const int yi = yrl[wm * 64 + im * 16 + lhi * 4 + reg];
#pragma unroll
                for (int in = 0; in < 4; ++in) {
                    float u  = acc[im][in][reg] * CU_L2;
                    float e  = fexp2(u);
                    float l2 = flog2(e + EPS_C);
                    sumL += l2;
                    sumU += (yi == yclv[in]) ? u : 0.f;
                }
            }
    } else {
#pragma unroll
        for (int im = 0; im < 4; ++im)
#pragma unroll
            for (int reg = 0; reg < 4; ++reg) {
                const int il = wm * 64 + im * 16 + lhi * 4 + reg;
                const int yi = yrl[il];
#pragma unroll
                for (int in = 0; in < 4; ++in) {
                    const int jl = wn * 64 + in * 16 + l16;
                    float u  = acc[im][in][reg] * CU_L2;
                    float e  = fexp2(u);
                    float l2 = flog2(e + EPS_C);
                    bool off = (il != jl);
                    sumL += off ? l2 : 0.f;
                    sumU += (off && yi == yclv[in]) ? u : 0.f;
                }
            }
    }

    float local = sumU - sumL;
    for (int m = 1; m < 64; m <<= 1) local += __shfl_xor(local, m);
    if (lane == 0) wsum[w] = local;
    __syncthreads();
    if (tid == 0)
        partials[blockIdx.y * gridDim.x + blockIdx.x] =
            ((double)wsum[0] + (double)wsum[1]) + ((double)wsum[2] + (double)wsum[3]);
}

// ---------------------------------------------------------------------------
// Finalize: sum partials; y histogram -> N_pos/N_neg;
// loss = -( ln2 * sum + N_neg * ln(eps) ) / B    (unchanged R10-proven)
// ---------------------------------------------------------------------------
__global__ __launch_bounds__(256) void finalize_kernel(
    const double* __restrict__ partials, const int* __restrict__ y,
    float* __restrict__ out)
{
    __shared__ double sh[4];
    __shared__ int hist[128];
    if (threadIdx.x < 128) hist[threadIdx.x] = 0;
    __syncthreads();
    for (int i = threadIdx.x; i < B_TOT; i += 256) atomicAdd(&hist[y[i]], 1);

    double loc = 0.0;
    for (int i = threadIdx.x; i < 4096; i += 256) loc += partials[i];
    for (int m = 1; m < 64; m <<= 1) loc += __shfl_xor(loc, m);
    int lane = threadIdx.x & 63, w = threadIdx.x >> 6;
    if (lane == 0) sh[w] = loc;
    __syncthreads();
    if (threadIdx.x == 0) {
        long long npos = 0;
        for (int c = 0; c < 128; ++c) {
            long long n = hist[c];
            npos += n * n;
        }
        npos -= B_TOT;   // remove diagonal
        long long nneg = (long long)B_TOT * (B_TOT - 1) - npos;
        double total = (sh[0] + sh[1]) + (sh[2] + sh[3]);
        out[0] = (float)(-(LN2_D * total + (double)nneg * LNEPS_D) / (double)B_TOT);
    }
}

// ---------------------------------------------------------------------------
extern "C" void kernel_launch(void* const* d_in, const int* in_sizes, int n_in,
                              void* d_out, int out_size, void* d_ws, size_t ws_size,
                              hipStream_t stream)
{
    // ws: [partials 32K][ssqs 32K][ssqt 32K][fs 2M][ft 2M][Ws16 512K][Wt16 512K]
    const size_t WS_NEEDED = (96 << 10) + (5 << 20);
    if (ws_size < WS_NEEDED) return;

    const float* f_s = (const float*)d_in[0];
    const float* f_t = (const float*)d_in[1];
    const int*   y   = (const int*)d_in[2];
    const float* W_s = (const float*)d_in[3];
    const float* b_s = (const float*)d_in[4];
    const float* W_t = (const float*)d_in[5];
    const float* b_t = (const float*)d_in[6];
    float* out = (float*)d_out;

    char* ws = (char*)d_ws;
    double* partials = (double*)ws;                               // 32 KB
    float*  ssqs = (float*)(ws + (32 << 10));                     // 32 KB
    float*  ssqt = (float*)(ws + (64 << 10));                     // 32 KB
    half_t* fs   = (half_t*)(ws + (96 << 10));                    // 2 MB
    half_t* ft   = (half_t*)(ws + (96 << 10) + (2 << 20));        // 2 MB
    half_t* Ws16 = (half_t*)(ws + (96 << 10) + (4 << 20));        // 512 KB
    half_t* Wt16 = (half_t*)(ws + (96 << 10) + (4 << 20) + (512 << 10));

    cvt_w_kernel<<<dim3(256, 2), 256, 0, stream>>>(W_s, W_t, Ws16, Wt16,
                                                   ssqs, ssqt);
    embed_mm_kernel<<<dim3(128, 2), 256, 0, stream>>>(f_s, f_t, Ws16, Wt16,
                                                      b_s, b_t, fs, ft,
                                                      ssqs, ssqt);
    embed_norm_kernel<<<dim3(256, 2), 256, 0, stream>>>(fs, ft, ssqs, ssqt);
    loss_kernel<<<dim3(64, 64), 256, 0, stream>>>(fs, ft, y, partials);
    finalize_kernel<<<1, 256, 0, stream>>>(partials, y, out);
    (void)in_sizes; (void)n_in; (void)out_size;
}